// Round 1
// baseline (603.868 us; speedup 1.0000x reference)
//
#include <hip/hip_runtime.h>
#include <math.h>

#define N_NODES 50000
#define N_EDGES 800000
#define IN_FEAT 128
#define HEADS   4
#define UNITS   16
#define OUTF    64          // HEADS*UNITS
#define LEAKY   0.2f

// ---- order-preserving float<->uint encoding for atomicMax on floats ----
__device__ __forceinline__ unsigned fkey(float f) {
    unsigned b = __float_as_uint(f);
    return (b & 0x80000000u) ? ~b : (b | 0x80000000u);
}
__device__ __forceinline__ float fdecode(unsigned k) {
    unsigned b = (k & 0x80000000u) ? (k & 0x7fffffffu) : ~k;
    return __uint_as_float(b);
}

// ---- zero out accumulators (d_out / denom) and segmax keys ----
__global__ __launch_bounds__(256) void init_kernel(float* __restrict__ out,
                                                   unsigned* __restrict__ segmax,
                                                   float* __restrict__ denom) {
    int i = blockIdx.x * 256 + threadIdx.x;
    if (i < N_NODES * OUTF) out[i] = 0.f;
    if (i < N_NODES * HEADS) { segmax[i] = 0u; denom[i] = 0.f; }
}

// ---- h = x @ W  (50000x128 @ 128x64), W staged in LDS (32 KB) ----
__global__ __launch_bounds__(256) void gemm_kernel(const float* __restrict__ x,
                                                   const float* __restrict__ W,
                                                   float* __restrict__ h) {
    __shared__ float Wl[IN_FEAT * OUTF];   // 32 KB
    __shared__ float xl[4 * IN_FEAT];      // 2 KB
    const int t = threadIdx.x;
    for (int i = t; i < IN_FEAT * OUTF; i += 256) Wl[i] = W[i];
    const int node0 = blockIdx.x * 4;
    for (int i = t; i < 4 * IN_FEAT; i += 256) {
        int n = node0 + (i >> 7);
        xl[i] = (n < N_NODES) ? x[n * IN_FEAT + (i & 127)] : 0.f;
    }
    __syncthreads();
    const int nl = t >> 6, col = t & 63;
    const int node = node0 + nl;
    float acc = 0.f;
    #pragma unroll 8
    for (int k = 0; k < IN_FEAT; ++k)
        acc += xl[nl * IN_FEAT + k] * Wl[k * OUTF + col];
    if (node < N_NODES) h[node * OUTF + col] = acc;
}

// ---- per-(node,head) attention scalars: a1 = <w1, h>, a2 = <w2, h> ----
__global__ __launch_bounds__(256) void node_att_kernel(const float* __restrict__ h,
                                                       const float* __restrict__ w1,
                                                       const float* __restrict__ w2,
                                                       float* __restrict__ a1,
                                                       float* __restrict__ a2) {
    int i = blockIdx.x * 256 + threadIdx.x;       // i = node*HEADS + head
    if (i >= N_NODES * HEADS) return;
    const int head = i & 3;
    const float* hp = h + i * UNITS;              // (i>>2)*64 + head*16 == i*16
    float s1 = 0.f, s2 = 0.f;
    #pragma unroll
    for (int u = 0; u < UNITS; ++u) {
        float v = hp[u];
        s1 += v * w1[head * UNITS + u];
        s2 += v * w2[head * UNITS + u];
    }
    a1[i] = s1;
    a2[i] = s2;
}

// ---- pass A: att[e,h] = leakyrelu(a1[snd,h]+a2[rcv,h]); segmax atomicMax ----
__global__ __launch_bounds__(256) void edge_att_kernel(const int* __restrict__ ei,
                                                       const float* __restrict__ a1,
                                                       const float* __restrict__ a2,
                                                       float* __restrict__ att,
                                                       unsigned* __restrict__ segmax) {
    int e = blockIdx.x * 256 + threadIdx.x;
    if (e >= N_EDGES) return;
    const int snd = ei[2 * e], rcv = ei[2 * e + 1];
    float4 v1 = *(const float4*)(a1 + snd * 4);
    float4 v2 = *(const float4*)(a2 + rcv * 4);
    float4 a;
    a.x = v1.x + v2.x; a.x = a.x > 0.f ? a.x : LEAKY * a.x;
    a.y = v1.y + v2.y; a.y = a.y > 0.f ? a.y : LEAKY * a.y;
    a.z = v1.z + v2.z; a.z = a.z > 0.f ? a.z : LEAKY * a.z;
    a.w = v1.w + v2.w; a.w = a.w > 0.f ? a.w : LEAKY * a.w;
    *(float4*)(att + e * 4) = a;
    atomicMax(&segmax[rcv * 4 + 0], fkey(a.x));
    atomicMax(&segmax[rcv * 4 + 1], fkey(a.y));
    atomicMax(&segmax[rcv * 4 + 2], fkey(a.z));
    atomicMax(&segmax[rcv * 4 + 3], fkey(a.w));
}

// ---- pass B: e = exp(att - segmax[rcv]); denom += e ----
__global__ __launch_bounds__(256) void edge_exp_kernel(const int* __restrict__ ei,
                                                       const unsigned* __restrict__ segmax,
                                                       float* __restrict__ att,
                                                       float* __restrict__ denom) {
    int e = blockIdx.x * 256 + threadIdx.x;
    if (e >= N_EDGES) return;
    const int rcv = ei[2 * e + 1];
    float4 a = *(float4*)(att + e * 4);
    uint4 m = *(const uint4*)(segmax + rcv * 4);
    a.x = expf(a.x - fdecode(m.x));
    a.y = expf(a.y - fdecode(m.y));
    a.z = expf(a.z - fdecode(m.z));
    a.w = expf(a.w - fdecode(m.w));
    *(float4*)(att + e * 4) = a;
    atomicAdd(&denom[rcv * 4 + 0], a.x);
    atomicAdd(&denom[rcv * 4 + 1], a.y);
    atomicAdd(&denom[rcv * 4 + 2], a.z);
    atomicAdd(&denom[rcv * 4 + 3], a.w);
}

// ---- pass C: out[rcv,c] += (e/denom[rcv,head]) * h[snd,c]; wave per edge ----
__global__ __launch_bounds__(256) void edge_aggr_kernel(const int* __restrict__ ei,
                                                        const float* __restrict__ h,
                                                        const float* __restrict__ eval_,
                                                        const float* __restrict__ denom,
                                                        float* __restrict__ out) {
    const int wave = threadIdx.x >> 6;
    const int lane = threadIdx.x & 63;
    const int e = blockIdx.x * 4 + wave;
    if (e >= N_EDGES) return;
    const int snd = ei[2 * e], rcv = ei[2 * e + 1];
    const int head = lane >> 4;
    const float alpha = eval_[e * 4 + head] / denom[rcv * 4 + head];
    const float v = h[snd * OUTF + lane] * alpha;
    atomicAdd(&out[rcv * OUTF + lane], v);
}

extern "C" void kernel_launch(void* const* d_in, const int* in_sizes, int n_in,
                              void* d_out, int out_size, void* d_ws, size_t ws_size,
                              hipStream_t stream) {
    const float* x  = (const float*)d_in[0];
    const int*   ei = (const int*)d_in[1];
    const float* W  = (const float*)d_in[2];
    const float* w1 = (const float*)d_in[3];
    const float* w2 = (const float*)d_in[4];
    float* out = (float*)d_out;

    // workspace layout (floats): h[3.2M] a1[200K] a2[200K] segmax[200K] denom[200K] att[3.2M]
    float*    h      = (float*)d_ws;
    float*    a1     = h + (size_t)N_NODES * OUTF;
    float*    a2     = a1 + (size_t)N_NODES * HEADS;
    unsigned* segmax = (unsigned*)(a2 + (size_t)N_NODES * HEADS);
    float*    denom  = (float*)(segmax + (size_t)N_NODES * HEADS);
    float*    att    = denom + (size_t)N_NODES * HEADS;

    const int initN = (N_NODES * OUTF + 255) / 256;
    init_kernel<<<initN, 256, 0, stream>>>(out, segmax, denom);
    gemm_kernel<<<(N_NODES + 3) / 4, 256, 0, stream>>>(x, W, h);
    node_att_kernel<<<(N_NODES * HEADS + 255) / 256, 256, 0, stream>>>(h, w1, w2, a1, a2);
    edge_att_kernel<<<(N_EDGES + 255) / 256, 256, 0, stream>>>(ei, a1, a2, att, segmax);
    edge_exp_kernel<<<(N_EDGES + 255) / 256, 256, 0, stream>>>(ei, segmax, att, denom);
    edge_aggr_kernel<<<(N_EDGES + 3) / 4, 256, 0, stream>>>(ei, h, att, denom, out);
}

// Round 2
// 342.614 us; speedup vs baseline: 1.7625x; 1.7625x over previous
//
#include <hip/hip_runtime.h>
#include <math.h>

#define N_NODES 50000
#define N_EDGES 800000
#define IN_FEAT 128
#define HEADS   4
#define UNITS   16
#define OUTF    64          // HEADS*UNITS
#define LEAKY   0.2f

// ---------------- zero the degree histogram ----------------
__global__ __launch_bounds__(256) void init_kernel(int* __restrict__ hist) {
    int i = blockIdx.x * 256 + threadIdx.x;
    if (i < N_NODES) hist[i] = 0;
}

// ---------------- h = x @ W : 64-node x 64-col tile, 4x4 per thread --------
// LDS: W 32 KB + x tile 64x132 floats (pad 4 to break bank alignment) = 33 KB
__global__ __launch_bounds__(256) void gemm_kernel(const float* __restrict__ x,
                                                   const float* __restrict__ W,
                                                   float* __restrict__ h) {
    __shared__ float Wl[IN_FEAT * OUTF];        // [k][c], 32 KB
    __shared__ float xl[64 * 132];              // [n][k], padded row 132
    const int t = threadIdx.x;
    const int node0 = blockIdx.x * 64;

    // stage W: 2048 float4s
    {
        const float4* W4 = (const float4*)W;
        #pragma unroll
        for (int it = 0; it < 8; ++it) {
            int idx = t + 256 * it;
            *(float4*)&Wl[idx * 4] = W4[idx];
        }
    }
    // stage x tile: 64 rows x 32 float4s
    {
        #pragma unroll
        for (int it = 0; it < 8; ++it) {
            int idx = t + 256 * it;          // 0..2047
            int r = idx >> 5, q4 = idx & 31;
            int node = node0 + r;
            float4 v = make_float4(0.f, 0.f, 0.f, 0.f);
            if (node < N_NODES) v = *(const float4*)(x + (size_t)node * IN_FEAT + q4 * 4);
            *(float4*)&xl[r * 132 + q4 * 4] = v;
        }
    }
    __syncthreads();

    const int c0 = (t & 15) * 4;       // 4 consecutive cols
    const int nbase = (t >> 4) * 4;    // 4 consecutive local nodes

    float acc[4][4];
    #pragma unroll
    for (int j = 0; j < 4; ++j)
        #pragma unroll
        for (int cc = 0; cc < 4; ++cc) acc[j][cc] = 0.f;

    #pragma unroll 4
    for (int k = 0; k < IN_FEAT; k += 4) {
        float4 wv[4], xv[4];
        #pragma unroll
        for (int kk = 0; kk < 4; ++kk) wv[kk] = *(float4*)&Wl[(k + kk) * OUTF + c0];
        #pragma unroll
        for (int j = 0; j < 4; ++j)   xv[j]  = *(float4*)&xl[(nbase + j) * 132 + k];
        #pragma unroll
        for (int j = 0; j < 4; ++j) {
            const float xk[4] = {xv[j].x, xv[j].y, xv[j].z, xv[j].w};
            #pragma unroll
            for (int kk = 0; kk < 4; ++kk) {
                acc[j][0] = fmaf(xk[kk], wv[kk].x, acc[j][0]);
                acc[j][1] = fmaf(xk[kk], wv[kk].y, acc[j][1]);
                acc[j][2] = fmaf(xk[kk], wv[kk].z, acc[j][2]);
                acc[j][3] = fmaf(xk[kk], wv[kk].w, acc[j][3]);
            }
        }
    }

    #pragma unroll
    for (int j = 0; j < 4; ++j) {
        int node = node0 + nbase + j;
        if (node < N_NODES)
            *(float4*)(h + (size_t)node * OUTF + c0) =
                make_float4(acc[j][0], acc[j][1], acc[j][2], acc[j][3]);
    }
}

// ---------------- per-(node,head) attention scalars ----------------
__global__ __launch_bounds__(256) void node_att_kernel(const float* __restrict__ h,
                                                       const float* __restrict__ w1,
                                                       const float* __restrict__ w2,
                                                       float* __restrict__ a1,
                                                       float* __restrict__ a2) {
    int i = blockIdx.x * 256 + threadIdx.x;       // i = node*HEADS + head
    if (i >= N_NODES * HEADS) return;
    const int head = i & 3;
    const float4* hp = (const float4*)(h + (size_t)i * UNITS);
    const float4* w1p = (const float4*)(w1 + head * UNITS);
    const float4* w2p = (const float4*)(w2 + head * UNITS);
    float s1 = 0.f, s2 = 0.f;
    #pragma unroll
    for (int u = 0; u < 4; ++u) {
        float4 v = hp[u], q1 = w1p[u], q2 = w2p[u];
        s1 += v.x * q1.x + v.y * q1.y + v.z * q1.z + v.w * q1.w;
        s2 += v.x * q2.x + v.y * q2.y + v.z * q2.z + v.w * q2.w;
    }
    a1[i] = s1;
    a2[i] = s2;
}

// ---------------- degree histogram over receivers ----------------
__global__ __launch_bounds__(256) void hist_kernel(const int2* __restrict__ ei,
                                                   int* __restrict__ hist) {
    int e = blockIdx.x * 256 + threadIdx.x;
    if (e >= N_EDGES) return;
    atomicAdd(&hist[ei[e].y], 1);
}

// ---------------- single-block exclusive scan (50000 elems) ----------------
__global__ __launch_bounds__(1024) void scan_kernel(const int* __restrict__ hist,
                                                    int* __restrict__ row_start,
                                                    int* __restrict__ cursor) {
    __shared__ int sums[1024];
    const int t = threadIdx.x;
    const int CH = (N_NODES + 1023) / 1024;       // 49
    const int beg = t * CH;
    const int fin = min(beg + CH, N_NODES);
    int s = 0;
    for (int i = beg; i < fin; ++i) s += hist[i];
    sums[t] = s;
    __syncthreads();
    // inclusive Hillis-Steele
    for (int off = 1; off < 1024; off <<= 1) {
        int v = (t >= off) ? sums[t - off] : 0;
        __syncthreads();
        sums[t] += v;
        __syncthreads();
    }
    int run = (t == 0) ? 0 : sums[t - 1];
    for (int i = beg; i < fin; ++i) {
        row_start[i] = run;
        cursor[i] = run;
        run += hist[i];
    }
    if (t == 1023) row_start[N_NODES] = run;      // == N_EDGES
}

// ---------------- scatter sender ids into CSR slots ----------------
__global__ __launch_bounds__(256) void scatter_kernel(const int2* __restrict__ ei,
                                                      int* __restrict__ cursor,
                                                      int* __restrict__ edge_snd) {
    int e = blockIdx.x * 256 + threadIdx.x;
    if (e >= N_EDGES) return;
    int2 v = ei[e];
    int pos = atomicAdd(&cursor[v.y], 1);
    edge_snd[pos] = v.x;
}

// ---------------- fused softmax + aggregation: one wave per node ----------
__global__ __launch_bounds__(256, 8) void gather_kernel(const int* __restrict__ row_start,
                                                        const int* __restrict__ edge_snd,
                                                        const float* __restrict__ a1,
                                                        const float* __restrict__ a2,
                                                        const float* __restrict__ h,
                                                        float* __restrict__ out) {
    const int wave = threadIdx.x >> 6;
    const int lane = threadIdx.x & 63;
    const int n = blockIdx.x * 4 + wave;
    if (n >= N_NODES) return;
    const int hc = lane >> 4;                      // head of this col
    const float a2h = a2[n * 4 + hc];
    const int base = row_start[n];
    const int end  = row_start[n + 1];

    float acc = 0.f, den = 0.f;
    int i = base;
    for (; i + 1 < end; i += 2) {
        int s0 = edge_snd[i], s1 = edge_snd[i + 1];
        float t0 = a1[s0 * 4 + hc] + a2h;
        float t1 = a1[s1 * 4 + hc] + a2h;
        float h0 = h[(size_t)s0 * OUTF + lane];
        float h1 = h[(size_t)s1 * OUTF + lane];
        t0 = t0 > 0.f ? t0 : LEAKY * t0;
        t1 = t1 > 0.f ? t1 : LEAKY * t1;
        float e0 = __expf(t0), e1 = __expf(t1);
        acc = fmaf(e0, h0, acc);
        acc = fmaf(e1, h1, acc);
        den += e0 + e1;
    }
    if (i < end) {
        int s0 = edge_snd[i];
        float t0 = a1[s0 * 4 + hc] + a2h;
        float h0 = h[(size_t)s0 * OUTF + lane];
        t0 = t0 > 0.f ? t0 : LEAKY * t0;
        float e0 = __expf(t0);
        acc = fmaf(e0, h0, acc);
        den += e0;
    }
    out[(size_t)n * OUTF + lane] = (end > base) ? acc / den : 0.f;
}

extern "C" void kernel_launch(void* const* d_in, const int* in_sizes, int n_in,
                              void* d_out, int out_size, void* d_ws, size_t ws_size,
                              hipStream_t stream) {
    const float* x  = (const float*)d_in[0];
    const int2*  ei = (const int2*)d_in[1];
    const float* W  = (const float*)d_in[2];
    const float* w1 = (const float*)d_in[3];
    const float* w2 = (const float*)d_in[4];
    float* out = (float*)d_out;

    // workspace layout
    float* h        = (float*)d_ws;                         // 3.2M floats
    float* a1       = h + (size_t)N_NODES * OUTF;           // 200K
    float* a2       = a1 + (size_t)N_NODES * HEADS;         // 200K
    int*   hist     = (int*)(a2 + (size_t)N_NODES * HEADS); // 50K
    int*   row_start= hist + N_NODES;                       // 50001
    int*   cursor   = row_start + N_NODES + 1;              // 50K
    int*   edge_snd = cursor + N_NODES;                     // 800K

    init_kernel<<<(N_NODES + 255) / 256, 256, 0, stream>>>(hist);
    gemm_kernel<<<(N_NODES + 63) / 64, 256, 0, stream>>>(x, W, h);
    node_att_kernel<<<(N_NODES * HEADS + 255) / 256, 256, 0, stream>>>(h, w1, w2, a1, a2);
    hist_kernel<<<(N_EDGES + 255) / 256, 256, 0, stream>>>(ei, hist);
    scan_kernel<<<1, 1024, 0, stream>>>(hist, row_start, cursor);
    scatter_kernel<<<(N_EDGES + 255) / 256, 256, 0, stream>>>(ei, cursor, edge_snd);
    gather_kernel<<<(N_NODES + 3) / 4, 256, 0, stream>>>(row_start, edge_snd, a1, a2, h, out);
}

// Round 3
// 251.593 us; speedup vs baseline: 2.4002x; 1.3618x over previous
//
#include <hip/hip_runtime.h>
#include <math.h>

#define N_NODES 50000
#define N_EDGES 800000
#define IN_FEAT 128
#define HEADS   4
#define UNITS   16
#define OUTF    64          // HEADS*UNITS
#define LEAKY   0.2f
#define NBLK    196         // ceil(N_NODES/256)

// ---------------- zero the degree histogram ----------------
__global__ __launch_bounds__(256) void init_kernel(int* __restrict__ hist) {
    int i = blockIdx.x * 256 + threadIdx.x;
    if (i < N_NODES) hist[i] = 0;
}

// ---------------- h = x @ W : 64-node x 64-col tile, 4x4 per thread --------
__global__ __launch_bounds__(256) void gemm_kernel(const float* __restrict__ x,
                                                   const float* __restrict__ W,
                                                   float* __restrict__ h) {
    __shared__ float Wl[IN_FEAT * OUTF];        // [k][c], 32 KB
    __shared__ float xl[64 * 132];              // [n][k], padded row 132
    const int t = threadIdx.x;
    const int node0 = blockIdx.x * 64;

    {
        const float4* W4 = (const float4*)W;
        #pragma unroll
        for (int it = 0; it < 8; ++it) {
            int idx = t + 256 * it;
            *(float4*)&Wl[idx * 4] = W4[idx];
        }
    }
    {
        #pragma unroll
        for (int it = 0; it < 8; ++it) {
            int idx = t + 256 * it;          // 0..2047
            int r = idx >> 5, q4 = idx & 31;
            int node = node0 + r;
            float4 v = make_float4(0.f, 0.f, 0.f, 0.f);
            if (node < N_NODES) v = *(const float4*)(x + (size_t)node * IN_FEAT + q4 * 4);
            *(float4*)&xl[r * 132 + q4 * 4] = v;
        }
    }
    __syncthreads();

    const int c0 = (t & 15) * 4;
    const int nbase = (t >> 4) * 4;

    float acc[4][4];
    #pragma unroll
    for (int j = 0; j < 4; ++j)
        #pragma unroll
        for (int cc = 0; cc < 4; ++cc) acc[j][cc] = 0.f;

    #pragma unroll 4
    for (int k = 0; k < IN_FEAT; k += 4) {
        float4 wv[4], xv[4];
        #pragma unroll
        for (int kk = 0; kk < 4; ++kk) wv[kk] = *(float4*)&Wl[(k + kk) * OUTF + c0];
        #pragma unroll
        for (int j = 0; j < 4; ++j)   xv[j]  = *(float4*)&xl[(nbase + j) * 132 + k];
        #pragma unroll
        for (int j = 0; j < 4; ++j) {
            const float xk[4] = {xv[j].x, xv[j].y, xv[j].z, xv[j].w};
            #pragma unroll
            for (int kk = 0; kk < 4; ++kk) {
                acc[j][0] = fmaf(xk[kk], wv[kk].x, acc[j][0]);
                acc[j][1] = fmaf(xk[kk], wv[kk].y, acc[j][1]);
                acc[j][2] = fmaf(xk[kk], wv[kk].z, acc[j][2]);
                acc[j][3] = fmaf(xk[kk], wv[kk].w, acc[j][3]);
            }
        }
    }

    #pragma unroll
    for (int j = 0; j < 4; ++j) {
        int node = node0 + nbase + j;
        if (node < N_NODES)
            *(float4*)(h + (size_t)node * OUTF + c0) =
                make_float4(acc[j][0], acc[j][1], acc[j][2], acc[j][3]);
    }
}

// ---------------- per-(node,head) attention scalars ----------------
__global__ __launch_bounds__(256) void node_att_kernel(const float* __restrict__ h,
                                                       const float* __restrict__ w1,
                                                       const float* __restrict__ w2,
                                                       float* __restrict__ a1,
                                                       float* __restrict__ a2) {
    int i = blockIdx.x * 256 + threadIdx.x;       // i = node*HEADS + head
    if (i >= N_NODES * HEADS) return;
    const int head = i & 3;
    const float4* hp = (const float4*)(h + (size_t)i * UNITS);
    const float4* w1p = (const float4*)(w1 + head * UNITS);
    const float4* w2p = (const float4*)(w2 + head * UNITS);
    float s1 = 0.f, s2 = 0.f;
    #pragma unroll
    for (int u = 0; u < 4; ++u) {
        float4 v = hp[u], q1 = w1p[u], q2 = w2p[u];
        s1 += v.x * q1.x + v.y * q1.y + v.z * q1.z + v.w * q1.w;
        s2 += v.x * q2.x + v.y * q2.y + v.z * q2.z + v.w * q2.w;
    }
    a1[i] = s1;
    a2[i] = s2;
}

// ---------------- degree histogram over receivers ----------------
__global__ __launch_bounds__(256) void hist_kernel(const int2* __restrict__ ei,
                                                   int* __restrict__ hist) {
    int e = blockIdx.x * 256 + threadIdx.x;
    if (e >= N_EDGES) return;
    atomicAdd(&hist[ei[e].y], 1);
}

// ---------------- 3-phase grid scan ----------------
// phase 1: per-block sums of 256-element chunks
__global__ __launch_bounds__(256) void scan_block_sums(const int* __restrict__ hist,
                                                       int* __restrict__ blocksum) {
    __shared__ int s[256];
    const int t = threadIdx.x;
    const int i = blockIdx.x * 256 + t;
    s[t] = (i < N_NODES) ? hist[i] : 0;
    __syncthreads();
    #pragma unroll
    for (int off = 128; off > 0; off >>= 1) {
        if (t < off) s[t] += s[t + off];
        __syncthreads();
    }
    if (t == 0) blocksum[blockIdx.x] = s[0];
}

// phase 2: single 256-wide scan of NBLK block sums
__global__ __launch_bounds__(256) void scan_tops(const int* __restrict__ blocksum,
                                                 int* __restrict__ blockoff,
                                                 int* __restrict__ row_start) {
    __shared__ int s[256];
    const int t = threadIdx.x;
    int v = (t < NBLK) ? blocksum[t] : 0;
    s[t] = v;
    __syncthreads();
    #pragma unroll
    for (int off = 1; off < 256; off <<= 1) {
        int u = (t >= off) ? s[t - off] : 0;
        __syncthreads();
        s[t] += u;
        __syncthreads();
    }
    if (t < NBLK) blockoff[t] = s[t] - v;          // exclusive
    if (t == 255) row_start[N_NODES] = s[255];     // total (== N_EDGES)
}

// phase 3: per-block exclusive scan + block offset → row_start, cursor
__global__ __launch_bounds__(256) void scan_final(const int* __restrict__ hist,
                                                  const int* __restrict__ blockoff,
                                                  int* __restrict__ row_start,
                                                  int* __restrict__ cursor) {
    __shared__ int s[256];
    const int t = threadIdx.x;
    const int i = blockIdx.x * 256 + t;
    int v = (i < N_NODES) ? hist[i] : 0;
    s[t] = v;
    __syncthreads();
    #pragma unroll
    for (int off = 1; off < 256; off <<= 1) {
        int u = (t >= off) ? s[t - off] : 0;
        __syncthreads();
        s[t] += u;
        __syncthreads();
    }
    if (i < N_NODES) {
        int excl = s[t] - v + blockoff[blockIdx.x];
        row_start[i] = excl;
        cursor[i] = excl;
    }
}

// ---------------- scatter sender ids into CSR slots ----------------
__global__ __launch_bounds__(256) void scatter_kernel(const int2* __restrict__ ei,
                                                      int* __restrict__ cursor,
                                                      int* __restrict__ edge_snd) {
    int e = blockIdx.x * 256 + threadIdx.x;
    if (e >= N_EDGES) return;
    int2 v = ei[e];
    int pos = atomicAdd(&cursor[v.y], 1);
    edge_snd[pos] = v.x;
}

// ---------------- fused softmax + aggregation: one wave per node ----------
__global__ __launch_bounds__(256, 8) void gather_kernel(const int* __restrict__ row_start,
                                                        const int* __restrict__ edge_snd,
                                                        const float* __restrict__ a1,
                                                        const float* __restrict__ a2,
                                                        const float* __restrict__ h,
                                                        float* __restrict__ out) {
    const int wave = threadIdx.x >> 6;
    const int lane = threadIdx.x & 63;
    const int n = blockIdx.x * 4 + wave;
    if (n >= N_NODES) return;
    const int hc = lane >> 4;                      // head of this col
    const float a2h = a2[n * 4 + hc];
    const int base = row_start[n];
    const int end  = row_start[n + 1];

    float acc = 0.f, den = 0.f;
    int i = base;
    for (; i + 1 < end; i += 2) {
        int s0 = edge_snd[i], s1 = edge_snd[i + 1];
        float t0 = a1[s0 * 4 + hc] + a2h;
        float t1 = a1[s1 * 4 + hc] + a2h;
        float h0 = h[(size_t)s0 * OUTF + lane];
        float h1 = h[(size_t)s1 * OUTF + lane];
        t0 = t0 > 0.f ? t0 : LEAKY * t0;
        t1 = t1 > 0.f ? t1 : LEAKY * t1;
        float e0 = __expf(t0), e1 = __expf(t1);
        acc = fmaf(e0, h0, acc);
        acc = fmaf(e1, h1, acc);
        den += e0 + e1;
    }
    if (i < end) {
        int s0 = edge_snd[i];
        float t0 = a1[s0 * 4 + hc] + a2h;
        float h0 = h[(size_t)s0 * OUTF + lane];
        t0 = t0 > 0.f ? t0 : LEAKY * t0;
        float e0 = __expf(t0);
        acc = fmaf(e0, h0, acc);
        den += e0;
    }
    out[(size_t)n * OUTF + lane] = (end > base) ? acc / den : 0.f;
}

extern "C" void kernel_launch(void* const* d_in, const int* in_sizes, int n_in,
                              void* d_out, int out_size, void* d_ws, size_t ws_size,
                              hipStream_t stream) {
    const float* x  = (const float*)d_in[0];
    const int2*  ei = (const int2*)d_in[1];
    const float* W  = (const float*)d_in[2];
    const float* w1 = (const float*)d_in[3];
    const float* w2 = (const float*)d_in[4];
    float* out = (float*)d_out;

    // workspace layout
    float* h        = (float*)d_ws;                         // 3.2M floats
    float* a1       = h + (size_t)N_NODES * OUTF;           // 200K
    float* a2       = a1 + (size_t)N_NODES * HEADS;         // 200K
    int*   hist     = (int*)(a2 + (size_t)N_NODES * HEADS); // 50K
    int*   row_start= hist + N_NODES;                       // 50001
    int*   cursor   = row_start + N_NODES + 1;              // 50K
    int*   edge_snd = cursor + N_NODES;                     // 800K
    int*   blocksum = edge_snd + N_EDGES;                   // NBLK
    int*   blockoff = blocksum + NBLK;                      // NBLK

    init_kernel<<<(N_NODES + 255) / 256, 256, 0, stream>>>(hist);
    gemm_kernel<<<(N_NODES + 63) / 64, 256, 0, stream>>>(x, W, h);
    node_att_kernel<<<(N_NODES * HEADS + 255) / 256, 256, 0, stream>>>(h, w1, w2, a1, a2);
    hist_kernel<<<(N_EDGES + 255) / 256, 256, 0, stream>>>(ei, hist);
    scan_block_sums<<<NBLK, 256, 0, stream>>>(hist, blocksum);
    scan_tops<<<1, 256, 0, stream>>>(blocksum, blockoff, row_start);
    scan_final<<<NBLK, 256, 0, stream>>>(hist, blockoff, row_start, cursor);
    scatter_kernel<<<(N_EDGES + 255) / 256, 256, 0, stream>>>(ei, cursor, edge_snd);
    gather_kernel<<<(N_NODES + 3) / 4, 256, 0, stream>>>(row_start, edge_snd, a1, a2, h, out);
}

// Round 4
// 215.605 us; speedup vs baseline: 2.8008x; 1.1669x over previous
//
#include <hip/hip_runtime.h>
#include <math.h>

#define N_NODES 50000
#define N_EDGES 800000
#define IN_FEAT 128
#define HEADS   4
#define UNITS   16
#define OUTF    64          // HEADS*UNITS
#define LEAKY   0.2f
#define NBLK    196         // ceil(N_NODES/256)
#define GEMM_BLKS 782       // ceil(N_NODES/64)
#define HIST_BLKS 3125      // N_EDGES/256

// ---- fused: [h = x@W + per-node attention scalars] | [receiver histogram] ----
// gemm blocks: 64-node x 64-col tile, 4x4 per thread; epilogue computes
// a1[n,h] = <w1[h], h[n,h,:]>, a2 likewise via shfl_xor(1,2) partial reduce.
// hist blocks (blockIdx >= GEMM_BLKS): 800K int atomics, overlapped with gemm.
__global__ __launch_bounds__(256) void fused_gemm_hist(const float* __restrict__ x,
                                                       const float* __restrict__ W,
                                                       const float* __restrict__ w1,
                                                       const float* __restrict__ w2,
                                                       const int2* __restrict__ ei,
                                                       float* __restrict__ h,
                                                       float* __restrict__ a1,
                                                       float* __restrict__ a2,
                                                       int* __restrict__ hist) {
    if (blockIdx.x >= GEMM_BLKS) {
        int e = (blockIdx.x - GEMM_BLKS) * 256 + threadIdx.x;
        if (e < N_EDGES) atomicAdd(&hist[ei[e].y], 1);
        return;
    }

    __shared__ float Wl[IN_FEAT * OUTF];        // [k][c], 32 KB
    __shared__ float xl[64 * 132];              // [n][k], padded row 132
    const int t = threadIdx.x;
    const int node0 = blockIdx.x * 64;

    {
        const float4* W4 = (const float4*)W;
        #pragma unroll
        for (int it = 0; it < 8; ++it) {
            int idx = t + 256 * it;
            *(float4*)&Wl[idx * 4] = W4[idx];
        }
    }
    {
        #pragma unroll
        for (int it = 0; it < 8; ++it) {
            int idx = t + 256 * it;          // 0..2047
            int r = idx >> 5, q4 = idx & 31;
            int node = node0 + r;
            float4 v = make_float4(0.f, 0.f, 0.f, 0.f);
            if (node < N_NODES) v = *(const float4*)(x + (size_t)node * IN_FEAT + q4 * 4);
            *(float4*)&xl[r * 132 + q4 * 4] = v;
        }
    }
    __syncthreads();

    const int c0 = (t & 15) * 4;       // 4 consecutive cols (within one head)
    const int nbase = (t >> 4) * 4;    // 4 consecutive local nodes

    float acc[4][4];
    #pragma unroll
    for (int j = 0; j < 4; ++j)
        #pragma unroll
        for (int cc = 0; cc < 4; ++cc) acc[j][cc] = 0.f;

    #pragma unroll 4
    for (int k = 0; k < IN_FEAT; k += 4) {
        float4 wv[4], xv[4];
        #pragma unroll
        for (int kk = 0; kk < 4; ++kk) wv[kk] = *(float4*)&Wl[(k + kk) * OUTF + c0];
        #pragma unroll
        for (int j = 0; j < 4; ++j)   xv[j]  = *(float4*)&xl[(nbase + j) * 132 + k];
        #pragma unroll
        for (int j = 0; j < 4; ++j) {
            const float xk[4] = {xv[j].x, xv[j].y, xv[j].z, xv[j].w};
            #pragma unroll
            for (int kk = 0; kk < 4; ++kk) {
                acc[j][0] = fmaf(xk[kk], wv[kk].x, acc[j][0]);
                acc[j][1] = fmaf(xk[kk], wv[kk].y, acc[j][1]);
                acc[j][2] = fmaf(xk[kk], wv[kk].z, acc[j][2]);
                acc[j][3] = fmaf(xk[kk], wv[kk].w, acc[j][3]);
            }
        }
    }

    // epilogue: store h + fused attention scalars
    // w1/w2 are [head][unit] flat = 64 floats; this thread's 4 cols are
    // exactly w1[c0..c0+3] (c0 = head*16 + unit0).
    const float4 w1v = *(const float4*)(w1 + c0);
    const float4 w2v = *(const float4*)(w2 + c0);
    const int head = (t & 15) >> 2;

    #pragma unroll
    for (int j = 0; j < 4; ++j) {
        const int node = node0 + nbase + j;
        if (node < N_NODES)
            *(float4*)(h + (size_t)node * OUTF + c0) =
                make_float4(acc[j][0], acc[j][1], acc[j][2], acc[j][3]);
        float p1 = acc[j][0] * w1v.x + acc[j][1] * w1v.y + acc[j][2] * w1v.z + acc[j][3] * w1v.w;
        float p2 = acc[j][0] * w2v.x + acc[j][1] * w2v.y + acc[j][2] * w2v.z + acc[j][3] * w2v.w;
        p1 += __shfl_xor(p1, 1, 64); p1 += __shfl_xor(p1, 2, 64);
        p2 += __shfl_xor(p2, 1, 64); p2 += __shfl_xor(p2, 2, 64);
        if ((t & 3) == 0 && node < N_NODES) {
            a1[node * 4 + head] = p1;
            a2[node * 4 + head] = p2;
        }
    }
}

// ---------------- 3-phase grid scan ----------------
__global__ __launch_bounds__(256) void scan_block_sums(const int* __restrict__ hist,
                                                       int* __restrict__ blocksum) {
    __shared__ int s[256];
    const int t = threadIdx.x;
    const int i = blockIdx.x * 256 + t;
    s[t] = (i < N_NODES) ? hist[i] : 0;
    __syncthreads();
    #pragma unroll
    for (int off = 128; off > 0; off >>= 1) {
        if (t < off) s[t] += s[t + off];
        __syncthreads();
    }
    if (t == 0) blocksum[blockIdx.x] = s[0];
}

__global__ __launch_bounds__(256) void scan_tops(const int* __restrict__ blocksum,
                                                 int* __restrict__ blockoff,
                                                 int* __restrict__ row_start) {
    __shared__ int s[256];
    const int t = threadIdx.x;
    int v = (t < NBLK) ? blocksum[t] : 0;
    s[t] = v;
    __syncthreads();
    #pragma unroll
    for (int off = 1; off < 256; off <<= 1) {
        int u = (t >= off) ? s[t - off] : 0;
        __syncthreads();
        s[t] += u;
        __syncthreads();
    }
    if (t < NBLK) blockoff[t] = s[t] - v;          // exclusive
    if (t == 255) row_start[N_NODES] = s[255];     // total (== N_EDGES)
}

__global__ __launch_bounds__(256) void scan_final(const int* __restrict__ hist,
                                                  const int* __restrict__ blockoff,
                                                  int* __restrict__ row_start,
                                                  int* __restrict__ cursor) {
    __shared__ int s[256];
    const int t = threadIdx.x;
    const int i = blockIdx.x * 256 + t;
    int v = (i < N_NODES) ? hist[i] : 0;
    s[t] = v;
    __syncthreads();
    #pragma unroll
    for (int off = 1; off < 256; off <<= 1) {
        int u = (t >= off) ? s[t - off] : 0;
        __syncthreads();
        s[t] += u;
        __syncthreads();
    }
    if (i < N_NODES) {
        int excl = s[t] - v + blockoff[blockIdx.x];
        row_start[i] = excl;
        cursor[i] = excl;
    }
}

// ---------------- scatter sender ids into CSR slots ----------------
__global__ __launch_bounds__(256) void scatter_kernel(const int2* __restrict__ ei,
                                                      int* __restrict__ cursor,
                                                      int* __restrict__ edge_snd) {
    int e = blockIdx.x * 256 + threadIdx.x;
    if (e >= N_EDGES) return;
    int2 v = ei[e];
    int pos = atomicAdd(&cursor[v.y], 1);
    edge_snd[pos] = v.x;
}

// ------- fused softmax+aggregation: wave/node, 4 edges x float4 per iter ----
__global__ __launch_bounds__(256, 8) void gather_kernel(const int* __restrict__ row_start,
                                                        const int* __restrict__ edge_snd,
                                                        const float* __restrict__ a1,
                                                        const float* __restrict__ a2,
                                                        const float* __restrict__ h,
                                                        float* __restrict__ out) {
    const int wave = threadIdx.x >> 6;
    const int lane = threadIdx.x & 63;
    const int n = blockIdx.x * 4 + wave;
    if (n >= N_NODES) return;
    const int sub  = lane >> 4;                    // edge slot 0..3
    const int li   = lane & 15;                    // float4 col group
    const int head = li >> 2;
    const float a2h = a2[n * 4 + head];
    const int base = row_start[n];
    const int end  = row_start[n + 1];
    const float4* h4 = (const float4*)h;

    float4 acc = make_float4(0.f, 0.f, 0.f, 0.f);
    float den = 0.f;

    for (int i = base; i < end; i += 8) {
        // half A: edges i..i+3 (slot = sub), mask-predicated
        {
            int eraw = i + sub;
            int eidx = min(eraw, end - 1);
            int s = edge_snd[eidx];
            float t0 = a1[s * 4 + head] + a2h;
            t0 = t0 > 0.f ? t0 : LEAKY * t0;
            float e = (eraw < end) ? __expf(t0) : 0.f;
            float4 hv = h4[(unsigned)(s * 16 + li)];
            acc.x = fmaf(e, hv.x, acc.x);
            acc.y = fmaf(e, hv.y, acc.y);
            acc.z = fmaf(e, hv.z, acc.z);
            acc.w = fmaf(e, hv.w, acc.w);
            den += e;
        }
        // half B: edges i+4..i+7
        {
            int eraw = i + 4 + sub;
            int eidx = min(eraw, end - 1);
            int s = edge_snd[eidx];
            float t0 = a1[s * 4 + head] + a2h;
            t0 = t0 > 0.f ? t0 : LEAKY * t0;
            float e = (eraw < end) ? __expf(t0) : 0.f;
            float4 hv = h4[(unsigned)(s * 16 + li)];
            acc.x = fmaf(e, hv.x, acc.x);
            acc.y = fmaf(e, hv.y, acc.y);
            acc.z = fmaf(e, hv.z, acc.z);
            acc.w = fmaf(e, hv.w, acc.w);
            den += e;
        }
    }

    // reduce across the 4 edge slots (lanes differing in bits 4,5)
    #pragma unroll
    for (int off = 16; off <= 32; off <<= 1) {
        acc.x += __shfl_xor(acc.x, off, 64);
        acc.y += __shfl_xor(acc.y, off, 64);
        acc.z += __shfl_xor(acc.z, off, 64);
        acc.w += __shfl_xor(acc.w, off, 64);
        den   += __shfl_xor(den,   off, 64);
    }

    if (sub == 0) {
        float inv = (end > base) ? 1.f / den : 0.f;
        *(float4*)(out + (size_t)n * OUTF + li * 4) =
            make_float4(acc.x * inv, acc.y * inv, acc.z * inv, acc.w * inv);
    }
}

extern "C" void kernel_launch(void* const* d_in, const int* in_sizes, int n_in,
                              void* d_out, int out_size, void* d_ws, size_t ws_size,
                              hipStream_t stream) {
    const float* x  = (const float*)d_in[0];
    const int2*  ei = (const int2*)d_in[1];
    const float* W  = (const float*)d_in[2];
    const float* w1 = (const float*)d_in[3];
    const float* w2 = (const float*)d_in[4];
    float* out = (float*)d_out;

    // workspace layout
    float* h        = (float*)d_ws;                         // 3.2M floats
    float* a1       = h + (size_t)N_NODES * OUTF;           // 200K
    float* a2       = a1 + (size_t)N_NODES * HEADS;         // 200K
    int*   hist     = (int*)(a2 + (size_t)N_NODES * HEADS); // 50K
    int*   row_start= hist + N_NODES;                       // 50001
    int*   cursor   = row_start + N_NODES + 1;              // 50K
    int*   edge_snd = cursor + N_NODES;                     // 800K
    int*   blocksum = edge_snd + N_EDGES;                   // NBLK
    int*   blockoff = blocksum + NBLK;                      // NBLK

    hipMemsetAsync(hist, 0, N_NODES * sizeof(int), stream);
    fused_gemm_hist<<<GEMM_BLKS + HIST_BLKS, 256, 0, stream>>>(x, W, w1, w2, ei,
                                                               h, a1, a2, hist);
    scan_block_sums<<<NBLK, 256, 0, stream>>>(hist, blocksum);
    scan_tops<<<1, 256, 0, stream>>>(blocksum, blockoff, row_start);
    scan_final<<<NBLK, 256, 0, stream>>>(hist, blockoff, row_start, cursor);
    scatter_kernel<<<(N_EDGES + 255) / 256, 256, 0, stream>>>(ei, cursor, edge_snd);
    gather_kernel<<<(N_NODES + 3) / 4, 256, 0, stream>>>(row_start, edge_snd, a1, a2, h, out);
}

// Round 5
// 179.982 us; speedup vs baseline: 3.3552x; 1.1979x over previous
//
#include <hip/hip_runtime.h>
#include <math.h>

#define N_NODES 50000
#define N_EDGES 800000
#define IN_FEAT 128
#define HEADS   4
#define UNITS   16
#define OUTF    64          // HEADS*UNITS
#define LEAKY   0.2f

#define NB      196         // buckets: rcv>>8, 256 nodes each
#define BCAP    5120        // bucket capacity (mean 4081, sigma 64 -> 16 sigma)
#define GEMM_BLKS 1563      // ceil(N_NODES/32)
#define A_BLOCKS  391       // ceil(N_EDGES/2048)
#define EPB     8           // edges per thread in phase A

union SharedU {
    struct { float Wl[IN_FEAT * OUTF]; float xl[32 * 132]; } g;   // 49.7 KB
    struct { int2 stage[2048]; int hist[256], s[256], excl[256],
             gbase[256], cur[256]; } a;                            // 37.9 KB
};

// ---- fused: [h = x@W + att scalars] (blocks < GEMM_BLKS) | [bucket scatter] ----
__global__ __launch_bounds__(256) void fused_gemm_bucketA(const float* __restrict__ x,
                                                          const float* __restrict__ W,
                                                          const float* __restrict__ w1,
                                                          const float* __restrict__ w2,
                                                          const int2* __restrict__ ei,
                                                          float* __restrict__ h,
                                                          float* __restrict__ a1,
                                                          float* __restrict__ a2,
                                                          int* __restrict__ bucket_cnt,
                                                          int2* __restrict__ buckets) {
    __shared__ SharedU sh;
    const int t = threadIdx.x;

    if (blockIdx.x >= GEMM_BLKS) {
        // ---------------- phase A: bucket scatter with LDS reorder ----------
        const int e0 = (blockIdx.x - GEMM_BLKS) * 2048;
        for (int i = t; i < 256; i += 256) sh.a.hist[i] = 0;
        __syncthreads();

        int2 ed[EPB]; int bk[EPB];
        #pragma unroll
        for (int j = 0; j < EPB; ++j) {
            int e = e0 + t + j * 256;
            if (e < N_EDGES) {
                ed[j] = ei[e];
                bk[j] = ed[j].y >> 8;
                atomicAdd(&sh.a.hist[bk[j]], 1);
            } else bk[j] = -1;
        }
        __syncthreads();
        // scan 256 (Hillis-Steele)
        int v = sh.a.hist[t];
        sh.a.s[t] = v;
        __syncthreads();
        #pragma unroll
        for (int off = 1; off < 256; off <<= 1) {
            int u = (t >= off) ? sh.a.s[t - off] : 0;
            __syncthreads();
            sh.a.s[t] += u;
            __syncthreads();
        }
        sh.a.excl[t] = sh.a.s[t] - v;
        sh.a.cur[t] = 0;
        if (t < NB) sh.a.gbase[t] = atomicAdd(&bucket_cnt[t], v);
        __syncthreads();
        // local sort into stage
        #pragma unroll
        for (int j = 0; j < EPB; ++j) {
            if (bk[j] >= 0) {
                int p = sh.a.excl[bk[j]] + atomicAdd(&sh.a.cur[bk[j]], 1);
                sh.a.stage[p] = ed[j];
            }
        }
        __syncthreads();
        // stream out: contiguous runs per bucket
        const int total = min(2048, N_EDGES - e0);
        for (int i = t; i < total; i += 256) {
            int2 vv = sh.a.stage[i];
            int b = vv.y >> 8;
            buckets[(size_t)b * BCAP + sh.a.gbase[b] + (i - sh.a.excl[b])] = vv;
        }
        return;
    }

    // ---------------- gemm: 32-node x 64-col tile, 2x4 per thread -----------
    const int node0 = blockIdx.x * 32;
    {
        const float4* W4 = (const float4*)W;
        #pragma unroll
        for (int it = 0; it < 8; ++it) {
            int idx = t + 256 * it;
            *(float4*)&sh.g.Wl[idx * 4] = W4[idx];
        }
        #pragma unroll
        for (int it = 0; it < 4; ++it) {
            int idx = t + 256 * it;            // 0..1023
            int r = idx >> 5, q4 = idx & 31;
            int node = node0 + r;
            float4 vx = make_float4(0.f, 0.f, 0.f, 0.f);
            if (node < N_NODES) vx = *(const float4*)(x + (size_t)node * IN_FEAT + q4 * 4);
            *(float4*)&sh.g.xl[r * 132 + q4 * 4] = vx;
        }
    }
    __syncthreads();

    const int c0 = (t & 15) * 4;       // 4 consecutive cols (one head)
    const int nbase = (t >> 4) * 2;    // 2 local nodes

    float acc[2][4];
    #pragma unroll
    for (int j = 0; j < 2; ++j)
        #pragma unroll
        for (int cc = 0; cc < 4; ++cc) acc[j][cc] = 0.f;

    #pragma unroll 4
    for (int k = 0; k < IN_FEAT; k += 4) {
        float4 wv[4], xv[2];
        #pragma unroll
        for (int kk = 0; kk < 4; ++kk) wv[kk] = *(float4*)&sh.g.Wl[(k + kk) * OUTF + c0];
        #pragma unroll
        for (int j = 0; j < 2; ++j)   xv[j]  = *(float4*)&sh.g.xl[(nbase + j) * 132 + k];
        #pragma unroll
        for (int j = 0; j < 2; ++j) {
            const float xk[4] = {xv[j].x, xv[j].y, xv[j].z, xv[j].w};
            #pragma unroll
            for (int kk = 0; kk < 4; ++kk) {
                acc[j][0] = fmaf(xk[kk], wv[kk].x, acc[j][0]);
                acc[j][1] = fmaf(xk[kk], wv[kk].y, acc[j][1]);
                acc[j][2] = fmaf(xk[kk], wv[kk].z, acc[j][2]);
                acc[j][3] = fmaf(xk[kk], wv[kk].w, acc[j][3]);
            }
        }
    }

    const float4 w1v = *(const float4*)(w1 + c0);
    const float4 w2v = *(const float4*)(w2 + c0);
    const int head = (t & 15) >> 2;

    #pragma unroll
    for (int j = 0; j < 2; ++j) {
        const int node = node0 + nbase + j;
        if (node < N_NODES)
            *(float4*)(h + (size_t)node * OUTF + c0) =
                make_float4(acc[j][0], acc[j][1], acc[j][2], acc[j][3]);
        float p1 = acc[j][0] * w1v.x + acc[j][1] * w1v.y + acc[j][2] * w1v.z + acc[j][3] * w1v.w;
        float p2 = acc[j][0] * w2v.x + acc[j][1] * w2v.y + acc[j][2] * w2v.z + acc[j][3] * w2v.w;
        p1 += __shfl_xor(p1, 1, 64); p1 += __shfl_xor(p1, 2, 64);
        p2 += __shfl_xor(p2, 1, 64); p2 += __shfl_xor(p2, 2, 64);
        if ((t & 3) == 0 && node < N_NODES) {
            a1[node * 4 + head] = p1;
            a2[node * 4 + head] = p2;
        }
    }
}

// ---------------- exclusive scan of 196 bucket counts ----------------
__global__ __launch_bounds__(256) void bucket_scan(const int* __restrict__ cnt,
                                                   int* __restrict__ base,
                                                   int* __restrict__ row_start) {
    __shared__ int s[256];
    const int t = threadIdx.x;
    int v = (t < NB) ? cnt[t] : 0;
    s[t] = v;
    __syncthreads();
    #pragma unroll
    for (int off = 1; off < 256; off <<= 1) {
        int u = (t >= off) ? s[t - off] : 0;
        __syncthreads();
        s[t] += u;
        __syncthreads();
    }
    if (t < NB) base[t] = s[t] - v;
    if (t == 255) row_start[N_NODES] = s[255];     // == N_EDGES
}

// ---------------- phase B: per-bucket counting sort -> CSR ----------------
__global__ __launch_bounds__(256) void bucketB(const int2* __restrict__ buckets,
                                               const int* __restrict__ bucket_cnt,
                                               const int* __restrict__ bucket_base,
                                               int* __restrict__ edge_snd,
                                               int* __restrict__ row_start) {
    __shared__ int hist[256], cur[256], s[256];
    __shared__ int snds[BCAP];                 // 20 KB
    const int b = blockIdx.x;
    const int t = threadIdx.x;
    const int cnt = bucket_cnt[b];
    const int gb  = bucket_base[b];
    hist[t] = 0;
    __syncthreads();
    for (int i = t; i < cnt; i += 256)
        atomicAdd(&hist[buckets[(size_t)b * BCAP + i].y & 255], 1);
    __syncthreads();
    int v = hist[t];
    s[t] = v;
    __syncthreads();
    #pragma unroll
    for (int off = 1; off < 256; off <<= 1) {
        int u = (t >= off) ? s[t - off] : 0;
        __syncthreads();
        s[t] += u;
        __syncthreads();
    }
    const int excl = s[t] - v;
    cur[t] = excl;
    const int node = b * 256 + t;
    if (node < N_NODES) row_start[node] = gb + excl;
    __syncthreads();
    for (int i = t; i < cnt; i += 256) {
        int2 vv = buckets[(size_t)b * BCAP + i];
        int p = atomicAdd(&cur[vv.y & 255], 1);
        snds[p] = vv.x;
    }
    __syncthreads();
    for (int i = t; i < cnt; i += 256) edge_snd[gb + i] = snds[i];
}

// ------- fused softmax+aggregation: wave/node, 4 edges x float4 per iter ----
__global__ __launch_bounds__(256, 8) void gather_kernel(const int* __restrict__ row_start,
                                                        const int* __restrict__ edge_snd,
                                                        const float* __restrict__ a1,
                                                        const float* __restrict__ a2,
                                                        const float* __restrict__ h,
                                                        float* __restrict__ out) {
    const int wave = threadIdx.x >> 6;
    const int lane = threadIdx.x & 63;
    const int n = blockIdx.x * 4 + wave;
    if (n >= N_NODES) return;
    const int sub  = lane >> 4;                    // edge slot 0..3
    const int li   = lane & 15;                    // float4 col group
    const int head = li >> 2;
    const int base = row_start[n];
    const int end  = row_start[n + 1];
    if (end <= base) {                             // degree-0: zero output
        if (sub == 0)
            *(float4*)(out + (size_t)n * OUTF + li * 4) = make_float4(0.f, 0.f, 0.f, 0.f);
        return;
    }
    const float a2h = a2[n * 4 + head];
    const float4* h4 = (const float4*)h;

    float4 acc = make_float4(0.f, 0.f, 0.f, 0.f);
    float den = 0.f;

    for (int i = base; i < end; i += 8) {
        {
            int eraw = i + sub;
            int eidx = min(eraw, end - 1);
            int s = edge_snd[eidx];
            float t0 = a1[s * 4 + head] + a2h;
            t0 = t0 > 0.f ? t0 : LEAKY * t0;
            float e = (eraw < end) ? __expf(t0) : 0.f;
            float4 hv = h4[(unsigned)(s * 16 + li)];
            acc.x = fmaf(e, hv.x, acc.x);
            acc.y = fmaf(e, hv.y, acc.y);
            acc.z = fmaf(e, hv.z, acc.z);
            acc.w = fmaf(e, hv.w, acc.w);
            den += e;
        }
        {
            int eraw = i + 4 + sub;
            int eidx = min(eraw, end - 1);
            int s = edge_snd[eidx];
            float t0 = a1[s * 4 + head] + a2h;
            t0 = t0 > 0.f ? t0 : LEAKY * t0;
            float e = (eraw < end) ? __expf(t0) : 0.f;
            float4 hv = h4[(unsigned)(s * 16 + li)];
            acc.x = fmaf(e, hv.x, acc.x);
            acc.y = fmaf(e, hv.y, acc.y);
            acc.z = fmaf(e, hv.z, acc.z);
            acc.w = fmaf(e, hv.w, acc.w);
            den += e;
        }
    }

    #pragma unroll
    for (int off = 16; off <= 32; off <<= 1) {
        acc.x += __shfl_xor(acc.x, off, 64);
        acc.y += __shfl_xor(acc.y, off, 64);
        acc.z += __shfl_xor(acc.z, off, 64);
        acc.w += __shfl_xor(acc.w, off, 64);
        den   += __shfl_xor(den,   off, 64);
    }

    if (sub == 0) {
        float inv = 1.f / den;
        *(float4*)(out + (size_t)n * OUTF + li * 4) =
            make_float4(acc.x * inv, acc.y * inv, acc.z * inv, acc.w * inv);
    }
}

extern "C" void kernel_launch(void* const* d_in, const int* in_sizes, int n_in,
                              void* d_out, int out_size, void* d_ws, size_t ws_size,
                              hipStream_t stream) {
    const float* x  = (const float*)d_in[0];
    const int2*  ei = (const int2*)d_in[1];
    const float* W  = (const float*)d_in[2];
    const float* w1 = (const float*)d_in[3];
    const float* w2 = (const float*)d_in[4];
    float* out = (float*)d_out;

    // workspace layout (bytes): h 12.8M | a1 0.8M | a2 0.8M | buckets 8.03M |
    //                           edge_snd 3.2M | row_start 200K | cnt/base ~2K
    float* h          = (float*)d_ws;
    float* a1         = h + (size_t)N_NODES * OUTF;
    float* a2         = a1 + (size_t)N_NODES * HEADS;
    int2*  buckets    = (int2*)(a2 + (size_t)N_NODES * HEADS);
    int*   edge_snd   = (int*)(buckets + (size_t)NB * BCAP);
    int*   row_start  = edge_snd + N_EDGES;
    int*   bucket_cnt = row_start + N_NODES + 1;
    int*   bucket_base= bucket_cnt + NB;

    hipMemsetAsync(bucket_cnt, 0, NB * sizeof(int), stream);
    fused_gemm_bucketA<<<GEMM_BLKS + A_BLOCKS, 256, 0, stream>>>(x, W, w1, w2, ei,
                                                                 h, a1, a2,
                                                                 bucket_cnt, buckets);
    bucket_scan<<<1, 256, 0, stream>>>(bucket_cnt, bucket_base, row_start);
    bucketB<<<NB, 256, 0, stream>>>(buckets, bucket_cnt, bucket_base, edge_snd, row_start);
    gather_kernel<<<(N_NODES + 3) / 4, 256, 0, stream>>>(row_start, edge_snd, a1, a2, h, out);
}

// Round 7
// 154.409 us; speedup vs baseline: 3.9108x; 1.1656x over previous
//
#include <hip/hip_runtime.h>
#include <math.h>

#define N_NODES 50000
#define N_EDGES 800000
#define IN_FEAT 128
#define HEADS   4
#define UNITS   16
#define OUTF    64          // HEADS*UNITS
#define LEAKY   0.2f

#define NB      196         // buckets: rcv>>8, 256 nodes each
#define BCAP    5120        // bucket capacity
#define GEMM_BLKS 782       // ceil(N_NODES/64)
#define A_BLOCKS  391       // ceil(N_EDGES/2048)
#define EPB     8           // edges per thread in phase A

typedef __attribute__((ext_vector_type(8))) short bf16x8;
typedef __attribute__((ext_vector_type(4))) float f32x4;

__device__ __forceinline__ unsigned short f2bf(float f) {
    unsigned u = __float_as_uint(f);
    unsigned r = u + 0x7FFFu + ((u >> 16) & 1u);   // RNE
    return (unsigned short)(r >> 16);
}

union SharedU {
    struct { unsigned short xl[64 * 136]; unsigned short wt[64 * 136]; } g; // 34816 B
    struct { int2 stage[2048]; int hist[256], s[256], excl[256],
             gbase[256], cur[256]; } a;                                     // 21504 B
};

// ---- one-time: W[k][c] fp32 -> Wt_g[c][k] bf16 (16 KB) ----
__global__ __launch_bounds__(256) void wt_prep(const float* __restrict__ W,
                                               unsigned short* __restrict__ Wt_g) {
    int idx = blockIdx.x * 256 + threadIdx.x;
    if (idx < IN_FEAT * OUTF) {
        int k = idx >> 6, c = idx & 63;
        Wt_g[c * IN_FEAT + k] = f2bf(W[idx]);
    }
}

// ---- fused: [h = x@W (MFMA bf16) + att scalars] | [bucket scatter] ----
__global__ __launch_bounds__(256) void fused_gemm_bucketA(const float* __restrict__ x,
                                                          const unsigned short* __restrict__ Wt_g,
                                                          const float* __restrict__ w1,
                                                          const float* __restrict__ w2,
                                                          const int2* __restrict__ ei,
                                                          unsigned short* __restrict__ hg,
                                                          float* __restrict__ a1,
                                                          float* __restrict__ a2,
                                                          int* __restrict__ bucket_cnt,
                                                          int2* __restrict__ buckets) {
    __shared__ SharedU sh;
    const int t = threadIdx.x;

    if (blockIdx.x >= GEMM_BLKS) {
        // ---------------- phase A: bucket scatter with LDS reorder ----------
        const int e0 = (blockIdx.x - GEMM_BLKS) * 2048;
        sh.a.hist[t] = 0;
        __syncthreads();

        int2 ed[EPB]; int bk[EPB];
        #pragma unroll
        for (int j = 0; j < EPB; ++j) {
            int e = e0 + t + j * 256;
            if (e < N_EDGES) {
                ed[j] = ei[e];
                bk[j] = ed[j].y >> 8;
                atomicAdd(&sh.a.hist[bk[j]], 1);
            } else bk[j] = -1;
        }
        __syncthreads();
        int v = sh.a.hist[t];
        sh.a.s[t] = v;
        __syncthreads();
        #pragma unroll
        for (int off = 1; off < 256; off <<= 1) {
            int u = (t >= off) ? sh.a.s[t - off] : 0;
            __syncthreads();
            sh.a.s[t] += u;
            __syncthreads();
        }
        sh.a.excl[t] = sh.a.s[t] - v;
        sh.a.cur[t] = 0;
        if (t < NB) sh.a.gbase[t] = atomicAdd(&bucket_cnt[t], v);
        __syncthreads();
        #pragma unroll
        for (int j = 0; j < EPB; ++j) {
            if (bk[j] >= 0) {
                int p = sh.a.excl[bk[j]] + atomicAdd(&sh.a.cur[bk[j]], 1);
                sh.a.stage[p] = ed[j];
            }
        }
        __syncthreads();
        const int total = min(2048, N_EDGES - e0);
        for (int i = t; i < total; i += 256) {
            int2 vv = sh.a.stage[i];
            int b = vv.y >> 8;
            buckets[(size_t)b * BCAP + sh.a.gbase[b] + (i - sh.a.excl[b])] = vv;
        }
        return;
    }

    // ---------------- MFMA gemm: 64 nodes x 64 cols, 4 waves ----------------
    const int node0 = blockIdx.x * 64;
    unsigned short* xl = sh.g.xl;   // [64][136] bf16 (pad 8)
    unsigned short* wt = sh.g.wt;   // [64][136] bf16

    // stage x tile (fp32 -> bf16): 2048 float4 units
    #pragma unroll
    for (int it = 0; it < 8; ++it) {
        int idx = t + 256 * it;
        int r = idx >> 5, q = idx & 31;
        int node = node0 + r;
        float4 v = make_float4(0.f, 0.f, 0.f, 0.f);
        if (node < N_NODES) v = *(const float4*)(x + (size_t)node * IN_FEAT + q * 4);
        ushort4 b;
        b.x = f2bf(v.x); b.y = f2bf(v.y); b.z = f2bf(v.z); b.w = f2bf(v.w);
        *(ushort4*)&xl[r * 136 + q * 4] = b;
    }
    // stage Wt (already bf16, coalesced): 2048 ushort4 units
    {
        const ushort4* Wt4 = (const ushort4*)Wt_g;
        #pragma unroll
        for (int it = 0; it < 8; ++it) {
            int idx = t + 256 * it;
            int c = idx >> 5, u = idx & 31;
            *(ushort4*)&wt[c * 136 + u * 4] = Wt4[idx];
        }
    }
    __syncthreads();

    const int lane = t & 63, wv = t >> 6;
    const int m = lane & 15, quad = lane >> 4;
    const int n0 = wv * 16;                       // wave's 16-node slab

    f32x4 acc[4] = {{0,0,0,0},{0,0,0,0},{0,0,0,0},{0,0,0,0}};
    #pragma unroll
    for (int kc = 0; kc < 4; ++kc) {
        bf16x8 af = *(bf16x8*)&xl[(n0 + m) * 136 + kc * 32 + quad * 8];
        #pragma unroll
        for (int ct = 0; ct < 4; ++ct) {
            bf16x8 bfr = *(bf16x8*)&wt[(ct * 16 + m) * 136 + kc * 32 + quad * 8];
            acc[ct] = __builtin_amdgcn_mfma_f32_16x16x32_bf16(af, bfr, acc[ct], 0, 0, 0);
        }
    }

    // a1/a2 from fp32 accumulators: head == ct; reduce over 16 cols (lane&15)
    #pragma unroll
    for (int ct = 0; ct < 4; ++ct) {
        const float u1 = w1[ct * 16 + m];
        const float u2 = w2[ct * 16 + m];
        #pragma unroll
        for (int r = 0; r < 4; ++r) {
            float p1 = acc[ct][r] * u1;
            float p2 = acc[ct][r] * u2;
            p1 += __shfl_xor(p1, 1, 64); p1 += __shfl_xor(p1, 2, 64);
            p1 += __shfl_xor(p1, 4, 64); p1 += __shfl_xor(p1, 8, 64);
            p2 += __shfl_xor(p2, 1, 64); p2 += __shfl_xor(p2, 2, 64);
            p2 += __shfl_xor(p2, 4, 64); p2 += __shfl_xor(p2, 8, 64);
            if (m == 0) {
                int node = node0 + n0 + quad * 4 + r;
                if (node < N_NODES) {
                    a1[node * 4 + ct] = p1;
                    a2[node * 4 + ct] = p2;
                }
            }
        }
    }

    // h epilogue: C-layout -> LDS bf16 [64][72] (144 B rows, 16B-aligned)
    // -> coalesced uint4 (8 cols) global stores.
    __syncthreads();
    unsigned short* hl = sh.g.xl;                 // reuse: 64*72 = 4608 ushort
    #pragma unroll
    for (int ct = 0; ct < 4; ++ct)
        #pragma unroll
        for (int r = 0; r < 4; ++r)
            hl[(n0 + quad * 4 + r) * 72 + ct * 16 + m] = f2bf(acc[ct][r]);
    __syncthreads();
    #pragma unroll
    for (int it = 0; it < 2; ++it) {
        int u = t + 256 * it;                     // 512 units: 64 rows x 8 groups
        int r = u >> 3, cg = u & 7;               // each group = 8 cols (uint4)
        int node = node0 + r;
        if (node < N_NODES)
            *(uint4*)&hg[(size_t)node * OUTF + cg * 8] = *(uint4*)&hl[r * 72 + cg * 8];
    }
}

// ---------------- exclusive scan of 196 bucket counts ----------------
__global__ __launch_bounds__(256) void bucket_scan(const int* __restrict__ cnt,
                                                   int* __restrict__ base,
                                                   int* __restrict__ row_start) {
    __shared__ int s[256];
    const int t = threadIdx.x;
    int v = (t < NB) ? cnt[t] : 0;
    s[t] = v;
    __syncthreads();
    #pragma unroll
    for (int off = 1; off < 256; off <<= 1) {
        int u = (t >= off) ? s[t - off] : 0;
        __syncthreads();
        s[t] += u;
        __syncthreads();
    }
    if (t < NB) base[t] = s[t] - v;
    if (t == 255) row_start[N_NODES] = s[255];     // == N_EDGES
}

// ---------------- phase B: per-bucket counting sort -> CSR ----------------
__global__ __launch_bounds__(256) void bucketB(const int2* __restrict__ buckets,
                                               const int* __restrict__ bucket_cnt,
                                               const int* __restrict__ bucket_base,
                                               int* __restrict__ edge_snd,
                                               int* __restrict__ row_start) {
    __shared__ int hist[256], cur[256], s[256];
    __shared__ int snds[BCAP];
    const int b = blockIdx.x;
    const int t = threadIdx.x;
    const int cnt = bucket_cnt[b];
    const int gb  = bucket_base[b];
    hist[t] = 0;
    __syncthreads();
    for (int i = t; i < cnt; i += 256)
        atomicAdd(&hist[buckets[(size_t)b * BCAP + i].y & 255], 1);
    __syncthreads();
    int v = hist[t];
    s[t] = v;
    __syncthreads();
    #pragma unroll
    for (int off = 1; off < 256; off <<= 1) {
        int u = (t >= off) ? s[t - off] : 0;
        __syncthreads();
        s[t] += u;
        __syncthreads();
    }
    const int excl = s[t] - v;
    cur[t] = excl;
    const int node = b * 256 + t;
    if (node < N_NODES) row_start[node] = gb + excl;
    __syncthreads();
    for (int i = t; i < cnt; i += 256) {
        int2 vv = buckets[(size_t)b * BCAP + i];
        int p = atomicAdd(&cur[vv.y & 255], 1);
        snds[p] = vv.x;
    }
    __syncthreads();
    for (int i = t; i < cnt; i += 256) edge_snd[gb + i] = snds[i];
}

// ------- fused softmax+aggregation: wave/node, 4 edges x bf16x4 per iter ----
__global__ __launch_bounds__(256, 8) void gather_kernel(const int* __restrict__ row_start,
                                                        const int* __restrict__ edge_snd,
                                                        const float* __restrict__ a1,
                                                        const float* __restrict__ a2,
                                                        const unsigned short* __restrict__ h,
                                                        float* __restrict__ out) {
    const int wave = threadIdx.x >> 6;
    const int lane = threadIdx.x & 63;
    const int n = blockIdx.x * 4 + wave;
    if (n >= N_NODES) return;
    const int sub  = lane >> 4;                    // edge slot 0..3
    const int li   = lane & 15;                    // bf16x4 col group
    const int head = li >> 2;
    const int base = row_start[n];
    const int end  = row_start[n + 1];
    if (end <= base) {
        if (sub == 0)
            *(float4*)(out + (size_t)n * OUTF + li * 4) = make_float4(0.f, 0.f, 0.f, 0.f);
        return;
    }
    const float a2h = a2[n * 4 + head];
    const ushort4* h4 = (const ushort4*)h;

    float4 acc = make_float4(0.f, 0.f, 0.f, 0.f);
    float den = 0.f;

    for (int i = base; i < end; i += 8) {
        {
            int eraw = i + sub;
            int eidx = min(eraw, end - 1);
            int s = edge_snd[eidx];
            float t0 = a1[s * 4 + head] + a2h;
            t0 = t0 > 0.f ? t0 : LEAKY * t0;
            float e = (eraw < end) ? __expf(t0) : 0.f;
            ushort4 hv = h4[(unsigned)(s * 16 + li)];
            acc.x = fmaf(e, __uint_as_float((unsigned)hv.x << 16), acc.x);
            acc.y = fmaf(e, __uint_as_float((unsigned)hv.y << 16), acc.y);
            acc.z = fmaf(e, __uint_as_float((unsigned)hv.z << 16), acc.z);
            acc.w = fmaf(e, __uint_as_float((unsigned)hv.w << 16), acc.w);
            den += e;
        }
        {
            int eraw = i + 4 + sub;
            int eidx = min(eraw, end - 1);
            int s = edge_snd[eidx];
            float t0 = a1[s * 4 + head] + a2h;
            t0 = t0 > 0.f ? t0 : LEAKY * t0;
            float e = (eraw < end) ? __expf(t0) : 0.f;
            ushort4 hv = h4[(unsigned)(s * 16 + li)];
            acc.x = fmaf(e, __uint_as_float((unsigned)hv.x << 16), acc.x);
            acc.y = fmaf(e, __uint_as_float((unsigned)hv.y << 16), acc.y);
            acc.z = fmaf(e, __uint_as_float((unsigned)hv.z << 16), acc.z);
            acc.w = fmaf(e, __uint_as_float((unsigned)hv.w << 16), acc.w);
            den += e;
        }
    }

    #pragma unroll
    for (int off = 16; off <= 32; off <<= 1) {
        acc.x += __shfl_xor(acc.x, off, 64);
        acc.y += __shfl_xor(acc.y, off, 64);
        acc.z += __shfl_xor(acc.z, off, 64);
        acc.w += __shfl_xor(acc.w, off, 64);
        den   += __shfl_xor(den,   off, 64);
    }

    if (sub == 0) {
        float inv = 1.f / den;
        *(float4*)(out + (size_t)n * OUTF + li * 4) =
            make_float4(acc.x * inv, acc.y * inv, acc.z * inv, acc.w * inv);
    }
}

extern "C" void kernel_launch(void* const* d_in, const int* in_sizes, int n_in,
                              void* d_out, int out_size, void* d_ws, size_t ws_size,
                              hipStream_t stream) {
    const float* x  = (const float*)d_in[0];
    const int2*  ei = (const int2*)d_in[1];
    const float* W  = (const float*)d_in[2];
    const float* w1 = (const float*)d_in[3];
    const float* w2 = (const float*)d_in[4];
    float* out = (float*)d_out;

    // workspace layout (bytes):
    // h bf16 6.4M | a1 0.8M | a2 0.8M | buckets 8.03M | edge_snd 3.2M |
    // row_start 200K | bucket_cnt/base ~2K | Wt_g 16K
    unsigned short* h = (unsigned short*)d_ws;
    float* a1         = (float*)(h + (size_t)N_NODES * OUTF);
    float* a2         = a1 + (size_t)N_NODES * HEADS;
    int2*  buckets    = (int2*)(a2 + (size_t)N_NODES * HEADS);
    int*   edge_snd   = (int*)(buckets + (size_t)NB * BCAP);
    int*   row_start  = edge_snd + N_EDGES;
    int*   bucket_cnt = row_start + N_NODES + 1;
    int*   bucket_base= bucket_cnt + NB;
    unsigned short* Wt_g = (unsigned short*)(bucket_base + NB);

    hipMemsetAsync(bucket_cnt, 0, NB * sizeof(int), stream);
    wt_prep<<<32, 256, 0, stream>>>(W, Wt_g);
    fused_gemm_bucketA<<<GEMM_BLKS + A_BLOCKS, 256, 0, stream>>>(x, Wt_g, w1, w2, ei,
                                                                 h, a1, a2,
                                                                 bucket_cnt, buckets);
    bucket_scan<<<1, 256, 0, stream>>>(bucket_cnt, bucket_base, row_start);
    bucketB<<<NB, 256, 0, stream>>>(buckets, bucket_cnt, bucket_base, edge_snd, row_start);
    gather_kernel<<<(N_NODES + 3) / 4, 256, 0, stream>>>(row_start, edge_snd, a1, a2, h, out);
}

// Round 9
// 135.620 us; speedup vs baseline: 4.4527x; 1.1385x over previous
//
#include <hip/hip_runtime.h>
#include <math.h>

#define N_NODES 50000
#define N_EDGES 800000
#define IN_FEAT 128
#define HEADS   4
#define UNITS   16
#define OUTF    64          // HEADS*UNITS
#define LEAKY   0.2f

#define NB      196         // buckets: rcv>>8, 256 nodes each
#define BCAP    5120        // bucket capacity
#define GEMM_BLKS 782       // ceil(N_NODES/64)
#define A_BLOCKS  391       // ceil(N_EDGES/2048)
#define EPB     8           // edges per thread in phase A

typedef __attribute__((ext_vector_type(8))) short bf16x8;
typedef __attribute__((ext_vector_type(4))) float f32x4;

__device__ __forceinline__ unsigned short f2bf(float f) {
    unsigned u = __float_as_uint(f);
    unsigned r = u + 0x7FFFu + ((u >> 16) & 1u);   // RNE
    return (unsigned short)(r >> 16);
}

union SharedU {
    struct { unsigned short xl[64 * 136]; unsigned short wt[64 * 136]; } g; // 34816 B
    struct { int2 stage[2048]; int hist[256], s[256], excl[256],
             gbase[256], cur[256]; } a;                                     // 21504 B
};

// ---- one-time: W[k][c] fp32 -> Wt_g[c][k] bf16; block 0 zeros bucket_cnt ----
__global__ __launch_bounds__(256) void wt_prep(const float* __restrict__ W,
                                               unsigned short* __restrict__ Wt_g,
                                               int* __restrict__ bucket_cnt) {
    int idx = blockIdx.x * 256 + threadIdx.x;
    if (blockIdx.x == 0 && threadIdx.x < NB) bucket_cnt[threadIdx.x] = 0;
    if (idx < IN_FEAT * OUTF) {
        int k = idx >> 6, c = idx & 63;
        Wt_g[c * IN_FEAT + k] = f2bf(W[idx]);
    }
}

// ---- fused: [h = x@W (MFMA bf16) + att scalars] | [bucket scatter] ----
__global__ __launch_bounds__(256) void fused_gemm_bucketA(const float* __restrict__ x,
                                                          const unsigned short* __restrict__ Wt_g,
                                                          const float* __restrict__ w1,
                                                          const float* __restrict__ w2,
                                                          const int2* __restrict__ ei,
                                                          unsigned short* __restrict__ hg,
                                                          float* __restrict__ a1,
                                                          float* __restrict__ a2,
                                                          int* __restrict__ bucket_cnt,
                                                          int2* __restrict__ buckets) {
    __shared__ SharedU sh;
    const int t = threadIdx.x;

    if (blockIdx.x >= GEMM_BLKS) {
        // ---------------- phase A: bucket scatter with LDS reorder ----------
        const int e0 = (blockIdx.x - GEMM_BLKS) * 2048;
        sh.a.hist[t] = 0;
        __syncthreads();

        int2 ed[EPB]; int bk[EPB];
        #pragma unroll
        for (int j = 0; j < EPB; ++j) {
            int e = e0 + t + j * 256;
            if (e < N_EDGES) {
                ed[j] = ei[e];
                bk[j] = ed[j].y >> 8;
                atomicAdd(&sh.a.hist[bk[j]], 1);
            } else bk[j] = -1;
        }
        __syncthreads();
        int v = sh.a.hist[t];
        sh.a.s[t] = v;
        __syncthreads();
        #pragma unroll
        for (int off = 1; off < 256; off <<= 1) {
            int u = (t >= off) ? sh.a.s[t - off] : 0;
            __syncthreads();
            sh.a.s[t] += u;
            __syncthreads();
        }
        sh.a.excl[t] = sh.a.s[t] - v;
        sh.a.cur[t] = 0;
        if (t < NB) sh.a.gbase[t] = atomicAdd(&bucket_cnt[t], v);
        __syncthreads();
        #pragma unroll
        for (int j = 0; j < EPB; ++j) {
            if (bk[j] >= 0) {
                int p = sh.a.excl[bk[j]] + atomicAdd(&sh.a.cur[bk[j]], 1);
                sh.a.stage[p] = ed[j];
            }
        }
        __syncthreads();
        const int total = min(2048, N_EDGES - e0);
        for (int i = t; i < total; i += 256) {
            int2 vv = sh.a.stage[i];
            int b = vv.y >> 8;
            buckets[(size_t)b * BCAP + sh.a.gbase[b] + (i - sh.a.excl[b])] = vv;
        }
        return;
    }

    // ---------------- MFMA gemm: 64 nodes x 64 cols, 4 waves ----------------
    const int node0 = blockIdx.x * 64;
    unsigned short* xl = sh.g.xl;   // [64][136] bf16 (pad 8)
    unsigned short* wt = sh.g.wt;   // [64][136] bf16

    #pragma unroll
    for (int it = 0; it < 8; ++it) {
        int idx = t + 256 * it;
        int r = idx >> 5, q = idx & 31;
        int node = node0 + r;
        float4 v = make_float4(0.f, 0.f, 0.f, 0.f);
        if (node < N_NODES) v = *(const float4*)(x + (size_t)node * IN_FEAT + q * 4);
        ushort4 b;
        b.x = f2bf(v.x); b.y = f2bf(v.y); b.z = f2bf(v.z); b.w = f2bf(v.w);
        *(ushort4*)&xl[r * 136 + q * 4] = b;
    }
    {
        const ushort4* Wt4 = (const ushort4*)Wt_g;
        #pragma unroll
        for (int it = 0; it < 8; ++it) {
            int idx = t + 256 * it;
            int c = idx >> 5, u = idx & 31;
            *(ushort4*)&wt[c * 136 + u * 4] = Wt4[idx];
        }
    }
    __syncthreads();

    const int lane = t & 63, wv = t >> 6;
    const int m = lane & 15, quad = lane >> 4;
    const int n0 = wv * 16;                       // wave's 16-node slab

    f32x4 acc[4] = {{0,0,0,0},{0,0,0,0},{0,0,0,0},{0,0,0,0}};
    #pragma unroll
    for (int kc = 0; kc < 4; ++kc) {
        bf16x8 af = *(bf16x8*)&xl[(n0 + m) * 136 + kc * 32 + quad * 8];
        #pragma unroll
        for (int ct = 0; ct < 4; ++ct) {
            bf16x8 bfr = *(bf16x8*)&wt[(ct * 16 + m) * 136 + kc * 32 + quad * 8];
            acc[ct] = __builtin_amdgcn_mfma_f32_16x16x32_bf16(af, bfr, acc[ct], 0, 0, 0);
        }
    }

    // a1/a2 from fp32 accumulators: head == ct; reduce over 16 cols (lane&15)
    #pragma unroll
    for (int ct = 0; ct < 4; ++ct) {
        const float u1 = w1[ct * 16 + m];
        const float u2 = w2[ct * 16 + m];
        #pragma unroll
        for (int r = 0; r < 4; ++r) {
            float p1 = acc[ct][r] * u1;
            float p2 = acc[ct][r] * u2;
            p1 += __shfl_xor(p1, 1, 64); p1 += __shfl_xor(p1, 2, 64);
            p1 += __shfl_xor(p1, 4, 64); p1 += __shfl_xor(p1, 8, 64);
            p2 += __shfl_xor(p2, 1, 64); p2 += __shfl_xor(p2, 2, 64);
            p2 += __shfl_xor(p2, 4, 64); p2 += __shfl_xor(p2, 8, 64);
            if (m == 0) {
                int node = node0 + n0 + quad * 4 + r;
                if (node < N_NODES) {
                    a1[node * 4 + ct] = p1;
                    a2[node * 4 + ct] = p2;
                }
            }
        }
    }

    // h epilogue: C-layout -> LDS bf16 [64][72] -> coalesced uint4 stores
    __syncthreads();
    unsigned short* hl = sh.g.xl;                 // reuse: 64*72 = 4608 ushort
    #pragma unroll
    for (int ct = 0; ct < 4; ++ct)
        #pragma unroll
        for (int r = 0; r < 4; ++r)
            hl[(n0 + quad * 4 + r) * 72 + ct * 16 + m] = f2bf(acc[ct][r]);
    __syncthreads();
    #pragma unroll
    for (int it = 0; it < 2; ++it) {
        int u = t + 256 * it;                     // 512 units: 64 rows x 8 groups
        int r = u >> 3, cg = u & 7;               // each group = 8 cols (uint4)
        int node = node0 + r;
        if (node < N_NODES)
            *(uint4*)&hg[(size_t)node * OUTF + cg * 8] = *(uint4*)&hl[r * 72 + cg * 8];
    }
}

// ---- phase B: per-bucket counting sort -> bucket-relative CSR (rs/re) ----
__global__ __launch_bounds__(256) void bucketB(const int2* __restrict__ buckets,
                                               const int* __restrict__ bucket_cnt,
                                               int* __restrict__ edge_snd,
                                               int* __restrict__ rs,
                                               int* __restrict__ re) {
    __shared__ int hist[256], cur[256], s[256];
    __shared__ int snds[BCAP];
    const int b = blockIdx.x;
    const int t = threadIdx.x;
    const int cnt = bucket_cnt[b];
    hist[t] = 0;
    __syncthreads();
    for (int i = t; i < cnt; i += 256)
        atomicAdd(&hist[buckets[(size_t)b * BCAP + i].y & 255], 1);
    __syncthreads();
    int v = hist[t];
    s[t] = v;
    __syncthreads();
    #pragma unroll
    for (int off = 1; off < 256; off <<= 1) {
        int u = (t >= off) ? s[t - off] : 0;
        __syncthreads();
        s[t] += u;
        __syncthreads();
    }
    const int excl = s[t] - v;
    cur[t] = excl;
    const int node = b * 256 + t;
    if (node < N_NODES) {
        rs[node] = b * BCAP + excl;
        re[node] = b * BCAP + excl + v;
    }
    __syncthreads();
    for (int i = t; i < cnt; i += 256) {
        int2 vv = buckets[(size_t)b * BCAP + i];
        int p = atomicAdd(&cur[vv.y & 255], 1);
        snds[p] = vv.x;
    }
    __syncthreads();
    for (int i = t; i < cnt; i += 256) edge_snd[(size_t)b * BCAP + i] = snds[i];
}

// ---- fused softmax+aggregation: wave/node, 8 edge slots x uint4 (8 cols) ----
__global__ __launch_bounds__(256, 8) void gather_kernel(const int* __restrict__ rs,
                                                        const int* __restrict__ re,
                                                        const int* __restrict__ edge_snd,
                                                        const float* __restrict__ a1,
                                                        const float* __restrict__ a2,
                                                        const unsigned short* __restrict__ h,
                                                        float* __restrict__ out) {
    const int wave = threadIdx.x >> 6;
    const int lane = threadIdx.x & 63;
    const int n = blockIdx.x * 4 + wave;
    if (n >= N_NODES) return;
    const int sub  = lane >> 3;                    // edge slot 0..7
    const int li   = lane & 7;                     // 8-col group
    const int head = li >> 1;
    const int base = rs[n];
    const int end  = re[n];
    if (end <= base) {
        if (sub == 0) {
            *(float4*)(out + (size_t)n * OUTF + li * 8)     = make_float4(0.f, 0.f, 0.f, 0.f);
            *(float4*)(out + (size_t)n * OUTF + li * 8 + 4) = make_float4(0.f, 0.f, 0.f, 0.f);
        }
        return;
    }
    const float a2h = a2[n * 4 + head];
    const uint4* h4 = (const uint4*)h;             // row = 8 uint4s

    float acc[8] = {0.f,0.f,0.f,0.f,0.f,0.f,0.f,0.f};
    float den = 0.f;

    for (int i = base; i < end; i += 16) {
        #pragma unroll
        for (int g = 0; g < 2; ++g) {
            int eraw = i + g * 8 + sub;
            int eidx = min(eraw, end - 1);
            int s = edge_snd[eidx];
            float t0 = a1[s * 4 + head] + a2h;
            t0 = t0 > 0.f ? t0 : LEAKY * t0;
            float e = (eraw < end) ? __expf(t0) : 0.f;
            uint4 hv = h4[(unsigned)(s * 8 + li)];
            const unsigned hw[4] = {hv.x, hv.y, hv.z, hv.w};
            #pragma unroll
            for (int q = 0; q < 4; ++q) {
                acc[q*2+0] = fmaf(e, __uint_as_float(hw[q] << 16),         acc[q*2+0]);
                acc[q*2+1] = fmaf(e, __uint_as_float(hw[q] & 0xFFFF0000u), acc[q*2+1]);
            }
            den += e;
        }
    }

    // reduce across the 8 edge slots (lane bits 3,4,5)
    #pragma unroll
    for (int off = 8; off <= 32; off <<= 1) {
        #pragma unroll
        for (int q = 0; q < 8; ++q) acc[q] += __shfl_xor(acc[q], off, 64);
        den += __shfl_xor(den, off, 64);
    }

    if (sub == 0) {
        float inv = 1.f / den;
        *(float4*)(out + (size_t)n * OUTF + li * 8) =
            make_float4(acc[0] * inv, acc[1] * inv, acc[2] * inv, acc[3] * inv);
        *(float4*)(out + (size_t)n * OUTF + li * 8 + 4) =
            make_float4(acc[4] * inv, acc[5] * inv, acc[6] * inv, acc[7] * inv);
    }
}

extern "C" void kernel_launch(void* const* d_in, const int* in_sizes, int n_in,
                              void* d_out, int out_size, void* d_ws, size_t ws_size,
                              hipStream_t stream) {
    const float* x  = (const float*)d_in[0];
    const int2*  ei = (const int2*)d_in[1];
    const float* W  = (const float*)d_in[2];
    const float* w1 = (const float*)d_in[3];
    const float* w2 = (const float*)d_in[4];
    float* out = (float*)d_out;

    // workspace layout (bytes):
    // h bf16 6.4M | a1 0.8M | a2 0.8M | buckets 8.03M | edge_snd 4.01M |
    // rs 200K | re 200K | bucket_cnt 784B | Wt_g 16K
    unsigned short* h = (unsigned short*)d_ws;
    float* a1         = (float*)(h + (size_t)N_NODES * OUTF);
    float* a2         = a1 + (size_t)N_NODES * HEADS;
    int2*  buckets    = (int2*)(a2 + (size_t)N_NODES * HEADS);
    int*   edge_snd   = (int*)(buckets + (size_t)NB * BCAP);
    int*   rs         = edge_snd + (size_t)NB * BCAP;
    int*   re         = rs + N_NODES;
    int*   bucket_cnt = re + N_NODES;
    unsigned short* Wt_g = (unsigned short*)(bucket_cnt + NB);

    wt_prep<<<32, 256, 0, stream>>>(W, Wt_g, bucket_cnt);
    fused_gemm_bucketA<<<GEMM_BLKS + A_BLOCKS, 256, 0, stream>>>(x, Wt_g, w1, w2, ei,
                                                                 h, a1, a2,
                                                                 bucket_cnt, buckets);
    bucketB<<<NB, 256, 0, stream>>>(buckets, bucket_cnt, edge_snd, rs, re);
    gather_kernel<<<(N_NODES + 3) / 4, 256, 0, stream>>>(rs, re, edge_snd, a1, a2, h, out);
}